// Round 6
// baseline (17747.038 us; speedup 1.0000x reference)
//
#include <hip/hip_runtime.h>
#include <hip/hip_bf16.h>
#include <hip/hip_cooperative_groups.h>

namespace cg = cooperative_groups;

// Problem constants (fixed shapes per reference setup_inputs; n_step = 200).
#define MM 64
#define NN 4096
#define KK 4096
#define NSTEP 200
#define NSLICE 8     // K-slices (block k = bx>>5)
#define NSTRIP 32    // 128-column strips (block s = bx&31; same-XCD per strip)
#define NPART 8      // P slices after intra-block kh pair reduction

typedef __bf16 bf16x8 __attribute__((ext_vector_type(8)));
typedef float  f32x4  __attribute__((ext_vector_type(4)));

static __device__ __forceinline__ unsigned short f2bf(float f) {
    __hip_bfloat16 h = __float2bfloat16(f);
    return __builtin_bit_cast(unsigned short, h);
}
static __device__ __forceinline__ float bf2f(unsigned short u) {
    __hip_bfloat16 h = __builtin_bit_cast(__hip_bfloat16, u);
    return __bfloat162float(h);
}

// Fragment layouts (mfma_f32_16x16x32_bf16, m89 mapping:
//   frag[lane=q*16+l16][j] = Mat[row16=l16][k=q*8+j]):
// A (g):  addr(m,kg) = ((kc*4 + (m>>4))*64 + q*16 + (m&15))*8 + j
// B (W):  addr(n,kg) = (((s*8 + ns)*128 + kc)*64 + q*16 + (n&15))*8 + j
// Partials P[part 8][s 32][row 64][col 128] fp32 (8 MB); part = k.

// ---------------------------------------------------------------------------
// Prologue 1: s = 0.5*(W[n][k]+W[k][n]), diag zero; (hi,lo) bf16 split,
// scattered into B-fragment order. 64x64 tiles, LDS transpose.
// ---------------------------------------------------------------------------
__global__ __launch_bounds__(256) void symm_kernel(const float* __restrict__ W,
                                                   unsigned short* __restrict__ Wfh,
                                                   unsigned short* __restrict__ Wfl) {
    __shared__ float T[64][65];
    const int tid = threadIdx.x;
    const int r0 = blockIdx.y * 64, c0 = blockIdx.x * 64;
#pragma unroll
    for (int i = 0; i < 4; ++i) {
        int lin = tid + i * 256;
        int cc  = lin >> 4;
        int r4  = (lin & 15) * 4;
        float4 v = *(const float4*)&W[(size_t)(c0 + cc) * NN + r0 + r4];
        T[cc][r4 + 0] = v.x; T[cc][r4 + 1] = v.y;
        T[cc][r4 + 2] = v.z; T[cc][r4 + 3] = v.w;
    }
    __syncthreads();
#pragma unroll
    for (int i = 0; i < 4; ++i) {
        int lin = tid + i * 256;
        int rr  = lin >> 4;
        int c4  = (lin & 15) * 4;
        float4 v = *(const float4*)&W[(size_t)(r0 + rr) * NN + c0 + c4];
        float d[4] = {v.x, v.y, v.z, v.w};
        ushort4 ohi, olo;
        unsigned short* ph = (unsigned short*)&ohi;
        unsigned short* pl = (unsigned short*)&olo;
#pragma unroll
        for (int j = 0; j < 4; ++j) {
            float sv = 0.5f * (d[j] + T[c4 + j][rr]);
            if (r0 + rr == c0 + c4 + j) sv = 0.0f;
            unsigned short hi = f2bf(sv);
            ph[j] = hi;
            pl[j] = f2bf(sv - bf2f(hi));
        }
        const int n  = r0 + rr;            // W row == output column
        const int kg = c0 + c4;            // 4-aligned
        const int s_ = n >> 7, ns = (n >> 4) & 7, ln = n & 15;
        const int kc = kg >> 5, q = (kg & 31) >> 3, j0 = kg & 7;
        size_t off = ((((size_t)(s_ * 8 + ns) * 128 + kc) * 64 + q * 16 + ln)) * 8 + j0;
        *(ushort4*)&Wfh[off] = ohi;        // 8B-aligned
        *(ushort4*)&Wfl[off] = olo;
    }
}

// ---------------------------------------------------------------------------
// Prologue 2: x0 = (1/beta)*log(g/(1-g)) (plain layout); g -> A-frag (hi,lo)
// ---------------------------------------------------------------------------
__global__ __launch_bounds__(256) void init_kernel(const float* __restrict__ g_in,
                                                   const float* __restrict__ beta,
                                                   float* __restrict__ x,
                                                   unsigned short* __restrict__ gfh,
                                                   unsigned short* __restrict__ gfl) {
    int idx = blockIdx.x * 256 + threadIdx.x;
    int r = idx >> 12, c = idx & (NN - 1);
    float g = g_in[idx];
    x[idx] = logf(g / (1.0f - g)) / beta[c];
    unsigned short hi = f2bf(g);
    unsigned short lo = f2bf(g - bf2f(hi));
    size_t off = (((size_t)(c >> 5) * 4 + (r >> 4)) * 64 + ((c & 31) >> 3) * 16 + (r & 15)) * 8 + (c & 7);
    gfh[off] = hi;
    gfl[off] = lo;
}

// ---------------------------------------------------------------------------
// Prologue 3: max_x = 50 / max(beta)
// ---------------------------------------------------------------------------
__global__ __launch_bounds__(256) void maxx_kernel(const float* __restrict__ beta,
                                                   float* __restrict__ out) {
    __shared__ float red[256];
    float m = -1e30f;
    for (int i = threadIdx.x; i < NN; i += 256) m = fmaxf(m, beta[i]);
    red[threadIdx.x] = m;
    __syncthreads();
    for (int s = 128; s > 0; s >>= 1) {
        if (threadIdx.x < s) red[threadIdx.x] = fmaxf(red[threadIdx.x], red[threadIdx.x + s]);
        __syncthreads();
    }
    if (threadIdx.x == 0) out[0] = 50.0f / red[0];
}

// ---------------------------------------------------------------------------
// Persistent cooperative kernel: all 200 steps in one launch.
// Grid 256 x 512. Block bx: k = bx>>5 (K-slice), s = bx&31 (strip; same-XCD).
// Per step:
//   Phase A: wave w (mh=w&1, nh=(w>>1)&1, kh=w>>2) computes its 32x64 corner
//     over its 256-wide K half; kh=1 waves dump acc to LDS, __syncthreads,
//     kh=0 waves add partner acc and write P[k][s] (64x128 fp32).
//   grid.sync()
//   Phase B (tid<128): 2 waves handle 128 vec8 epilogue tasks: sum 8 partials,
//     b/alpha/clip/sigmoid, update x, write next-step g A-frags (hi,lo).
//   grid.sync()
// ---------------------------------------------------------------------------
__global__ __launch_bounds__(512, 2) void run_kernel(
    unsigned short* __restrict__ g0h, unsigned short* __restrict__ g0l,
    unsigned short* __restrict__ g1h, unsigned short* __restrict__ g1l,
    float* __restrict__ x,
    const unsigned short* __restrict__ Wfh,
    const unsigned short* __restrict__ Wfl,
    const float* __restrict__ bvec,
    const float* __restrict__ beta,
    const float* __restrict__ tau,
    const float* __restrict__ dt_ptr,
    const float* __restrict__ maxx_ptr,
    float* __restrict__ P,
    float* __restrict__ gout_f32)
{
    cg::grid_group grid = cg::this_grid();

    __shared__ float sacc[4][32][64];   // 32 KB: kh=1 wave acc dump

    const int tid  = threadIdx.x;
    const int w    = tid >> 6;
    const int lane = tid & 63;
    const int q    = lane >> 4;
    const int l16  = lane & 15;

    const int bx = blockIdx.x;
    const int k  = bx >> 5;        // K-slice 0..7
    const int s  = bx & 31;        // strip 0..31 (bx%8 == s%8 -> same XCD)

    const int mh = w & 1;
    const int nh = (w >> 1) & 1;
    const int kh = w >> 2;

    const float dt = *dt_ptr;
    const float mx = *maxx_ptr;

    for (int st = 0; st < NSTEP; ++st) {
        const unsigned short* gih = (st & 1) ? g1h : g0h;
        const unsigned short* gil = (st & 1) ? g1l : g0l;
        unsigned short* goh = (st & 1) ? g0h : g1h;
        unsigned short* gol = (st & 1) ? g0l : g1l;

        // ---------------- Phase A: GEMM partials ----------------
        f32x4 acc[2][4] = {};
#pragma unroll
        for (int it = 0; it < 8; ++it) {
            const int kc = k * 16 + kh * 8 + it;
            const size_t aBase = ((size_t)kc * 4) * 512 + lane * 8;
            const size_t bBase = (((size_t)(s * 8) * 128 + kc) * 64 + lane) * 8;
            bf16x8 ah[2], al[2], bh[4], bl[4];
#pragma unroll
            for (int mi = 0; mi < 2; ++mi) {
                const size_t a = aBase + (size_t)(mh * 2 + mi) * 512;
                ah[mi] = *(const bf16x8*)&gih[a];
                al[mi] = *(const bf16x8*)&gil[a];
            }
#pragma unroll
            for (int ni = 0; ni < 4; ++ni) {
                const size_t b = bBase + (size_t)(nh * 4 + ni) * 128 * 512;
                bh[ni] = *(const bf16x8*)&Wfh[b];
                bl[ni] = *(const bf16x8*)&Wfl[b];
            }
#pragma unroll
            for (int mi = 0; mi < 2; ++mi)
#pragma unroll
                for (int ni = 0; ni < 4; ++ni) {
                    acc[mi][ni] = __builtin_amdgcn_mfma_f32_16x16x32_bf16(ah[mi], bh[ni], acc[mi][ni], 0, 0, 0);
                    acc[mi][ni] = __builtin_amdgcn_mfma_f32_16x16x32_bf16(al[mi], bh[ni], acc[mi][ni], 0, 0, 0);
                    acc[mi][ni] = __builtin_amdgcn_mfma_f32_16x16x32_bf16(ah[mi], bl[ni], acc[mi][ni], 0, 0, 0);
                }
        }

        if (kh == 1) {
#pragma unroll
            for (int mi = 0; mi < 2; ++mi)
#pragma unroll
                for (int ni = 0; ni < 4; ++ni)
#pragma unroll
                    for (int rg = 0; rg < 4; ++rg)
                        sacc[w - 4][(mi * 4 + ni) * 4 + rg][lane] = acc[mi][ni][rg];
        }
        __syncthreads();
        if (kh == 0) {
            float* Pb = &P[((size_t)(k * NSTRIP + s) * 64) * 128];
#pragma unroll
            for (int mi = 0; mi < 2; ++mi)
#pragma unroll
                for (int ni = 0; ni < 4; ++ni)
#pragma unroll
                    for (int rg = 0; rg < 4; ++rg) {
                        const int row = mh * 32 + mi * 16 + q * 4 + rg;
                        const int col = nh * 64 + ni * 16 + l16;
                        const float v = acc[mi][ni][rg] + sacc[w][(mi * 4 + ni) * 4 + rg][lane];
                        Pb[(size_t)row * 128 + col] = v;
                    }
        }

        grid.sync();   // P ready

        // ---------------- Phase B: epilogue (2 waves/block) ----------------
        if (tid < 128) {
            const int task = bx * 128 + tid;        // 0..32767
            const int m  = task >> 9;
            const int n0 = (task & 511) * 8;
            const int se = n0 >> 7;

            float sum[8] = {};
#pragma unroll
            for (int kp = 0; kp < NPART; ++kp) {
                const float* p = &P[((size_t)(kp * NSTRIP + se) * 64 + m) * 128 + (n0 & 127)];
                float4 p0 = *(const float4*)&p[0];
                float4 p1 = *(const float4*)&p[4];
                sum[0] += p0.x; sum[1] += p0.y; sum[2] += p0.z; sum[3] += p0.w;
                sum[4] += p1.x; sum[5] += p1.y; sum[6] += p1.z; sum[7] += p1.w;
            }

            float4 b0 = *(const float4*)&bvec[n0], b1 = *(const float4*)&bvec[n0 + 4];
            float4 e0 = *(const float4*)&beta[n0], e1 = *(const float4*)&beta[n0 + 4];
            float4 t0 = *(const float4*)&tau[n0],  t1 = *(const float4*)&tau[n0 + 4];
            float bb[8] = {b0.x, b0.y, b0.z, b0.w, b1.x, b1.y, b1.z, b1.w};
            float be[8] = {e0.x, e0.y, e0.z, e0.w, e1.x, e1.y, e1.z, e1.w};
            float tv[8] = {t0.x, t0.y, t0.z, t0.w, t1.x, t1.y, t1.z, t1.w};

            float* xp = &x[(size_t)m * NN + n0];
            float4 x0 = *(const float4*)&xp[0], x1 = *(const float4*)&xp[4];
            float xo[8] = {x0.x, x0.y, x0.z, x0.w, x1.x, x1.y, x1.z, x1.w};

            float gg[8];
            unsigned short vh[8], vl[8];
#pragma unroll
            for (int j = 0; j < 8; ++j) {
                const float al = dt / tv[j];
                float xn = al * (sum[j] + bb[j]) + (1.0f - al) * xo[j];
                xn = fminf(fmaxf(xn, -mx), mx);
                float g = 1.0f / (1.0f + __expf(-be[j] * xn));
                xo[j] = xn;
                gg[j] = g;
                unsigned short hi = f2bf(g);
                vh[j] = hi;
                vl[j] = f2bf(g - bf2f(hi));
            }
            *(float4*)&xp[0] = {xo[0], xo[1], xo[2], xo[3]};
            *(float4*)&xp[4] = {xo[4], xo[5], xo[6], xo[7]};

            size_t off = (((size_t)(n0 >> 5) * 4 + (m >> 4)) * 64 + ((n0 & 31) >> 3) * 16 + (m & 15)) * 8;
            *(ushort4*)&goh[off]     = {vh[0], vh[1], vh[2], vh[3]};
            *(ushort4*)&goh[off + 4] = {vh[4], vh[5], vh[6], vh[7]};
            *(ushort4*)&gol[off]     = {vl[0], vl[1], vl[2], vl[3]};
            *(ushort4*)&gol[off + 4] = {vl[4], vl[5], vl[6], vl[7]};

            if (st == NSTEP - 1) {
                *(float4*)&gout_f32[(size_t)m * NN + n0]     = {gg[0], gg[1], gg[2], gg[3]};
                *(float4*)&gout_f32[(size_t)m * NN + n0 + 4] = {gg[4], gg[5], gg[6], gg[7]};
            }
        }

        grid.sync();   // next-step g ready
    }
}

// ---------------------------------------------------------------------------
extern "C" void kernel_launch(void* const* d_in, const int* in_sizes, int n_in,
                              void* d_out, int out_size, void* d_ws, size_t ws_size,
                              hipStream_t stream) {
    const float* state_g = (const float*)d_in[0];
    const float* W       = (const float*)d_in[1];
    const float* b       = (const float*)d_in[2];
    const float* beta    = (const float*)d_in[3];
    const float* tau     = (const float*)d_in[4];
    const float* dt      = (const float*)d_in[5];
    float* out = (float*)d_out;

    char* ws = (char*)d_ws;
    const size_t WH = (size_t)KK * NN * 2;    // 32 MB per W-frag array
    const size_t XB = (size_t)MM * NN * 4;    // 1 MB
    const size_t GB = (size_t)MM * NN * 2;    // 512 KB per g-frag array
    const size_t PB = (size_t)NPART * NSTRIP * 64 * 128 * 4;   // 8 MB
    unsigned short* Wfh = (unsigned short*)ws;
    unsigned short* Wfl = (unsigned short*)(ws + WH);
    float*          x   = (float*)(ws + 2 * WH);
    unsigned short* g0h = (unsigned short*)(ws + 2 * WH + XB);
    unsigned short* g0l = (unsigned short*)(ws + 2 * WH + XB + GB);
    unsigned short* g1h = (unsigned short*)(ws + 2 * WH + XB + 2 * GB);
    unsigned short* g1l = (unsigned short*)(ws + 2 * WH + XB + 3 * GB);
    float*          P   = (float*)(ws + 2 * WH + XB + 4 * GB);
    float*          mxp = (float*)(ws + 2 * WH + XB + 4 * GB + PB);

    symm_kernel<<<dim3(64, 64), 256, 0, stream>>>(W, Wfh, Wfl);
    init_kernel<<<(MM * NN) / 256, 256, 0, stream>>>(state_g, beta, x, g0h, g0l);
    maxx_kernel<<<1, 256, 0, stream>>>(beta, mxp);

    void* args[] = {
        (void*)&g0h, (void*)&g0l, (void*)&g1h, (void*)&g1l,
        (void*)&x, (void*)&Wfh, (void*)&Wfl,
        (void*)&b, (void*)&beta, (void*)&tau, (void*)&dt, (void*)&mxp,
        (void*)&P, (void*)&out
    };
    hipLaunchCooperativeKernel((const void*)run_kernel, dim3(256), dim3(512),
                               args, 0, stream);
}

// Round 7
// 16368.564 us; speedup vs baseline: 1.0842x; 1.0842x over previous
//
#include <hip/hip_runtime.h>
#include <hip/hip_bf16.h>

// Problem constants (fixed shapes per reference setup_inputs; n_step = 200).
#define MM 64
#define NN 4096
#define KK 4096
#define NSTEP 200
#define NSLICE 8     // K-slice blocks per strip (block k = bx>>5)
#define NSTRIP 32    // 128-column strips (block s = bx&31; bx%8==s%8 -> same XCD)
#define NPART 8      // P slices (after intra-block kh pair reduction)

typedef __bf16 bf16x8 __attribute__((ext_vector_type(8)));
typedef float  f32x4  __attribute__((ext_vector_type(4)));

static __device__ __forceinline__ unsigned short f2bf(float f) {
    __hip_bfloat16 h = __float2bfloat16(f);
    return __builtin_bit_cast(unsigned short, h);
}
static __device__ __forceinline__ float bf2f(unsigned short u) {
    __hip_bfloat16 h = __builtin_bit_cast(__hip_bfloat16, u);
    return __bfloat162float(h);
}

// Fragment layouts (mfma_f32_16x16x32_bf16, m89 mapping:
//   frag[lane=q*16+l16][j] = Mat[row16=l16][k=q*8+j]):
// A (g):  addr(m,kg) = ((kc*4 + (m>>4))*64 + q*16 + (m&15))*8 + j
// B (W):  addr(n,kg) = (((s*8 + ns)*128 + kc)*64 + q*16 + (n&15))*8 + j
// Partials P[part 8][s 32][row 64][col 128] fp32 (8 MB); part = k.

// ---------------------------------------------------------------------------
// Prologue 1: s = 0.5*(W[n][k]+W[k][n]), diag zero; (hi,lo) bf16 split,
// scattered into B-fragment order. 64x64 tiles, LDS transpose.
// ---------------------------------------------------------------------------
__global__ __launch_bounds__(256) void symm_kernel(const float* __restrict__ W,
                                                   unsigned short* __restrict__ Wfh,
                                                   unsigned short* __restrict__ Wfl) {
    __shared__ float T[64][65];
    const int tid = threadIdx.x;
    const int r0 = blockIdx.y * 64, c0 = blockIdx.x * 64;
#pragma unroll
    for (int i = 0; i < 4; ++i) {
        int lin = tid + i * 256;
        int cc  = lin >> 4;
        int r4  = (lin & 15) * 4;
        float4 v = *(const float4*)&W[(size_t)(c0 + cc) * NN + r0 + r4];
        T[cc][r4 + 0] = v.x; T[cc][r4 + 1] = v.y;
        T[cc][r4 + 2] = v.z; T[cc][r4 + 3] = v.w;
    }
    __syncthreads();
#pragma unroll
    for (int i = 0; i < 4; ++i) {
        int lin = tid + i * 256;
        int rr  = lin >> 4;
        int c4  = (lin & 15) * 4;
        float4 v = *(const float4*)&W[(size_t)(r0 + rr) * NN + c0 + c4];
        float d[4] = {v.x, v.y, v.z, v.w};
        ushort4 ohi, olo;
        unsigned short* ph = (unsigned short*)&ohi;
        unsigned short* pl = (unsigned short*)&olo;
#pragma unroll
        for (int j = 0; j < 4; ++j) {
            float sv = 0.5f * (d[j] + T[c4 + j][rr]);
            if (r0 + rr == c0 + c4 + j) sv = 0.0f;
            unsigned short hi = f2bf(sv);
            ph[j] = hi;
            pl[j] = f2bf(sv - bf2f(hi));
        }
        const int n  = r0 + rr;            // W row == output column
        const int kg = c0 + c4;            // 4-aligned
        const int s_ = n >> 7, ns = (n >> 4) & 7, ln = n & 15;
        const int kc = kg >> 5, q = (kg & 31) >> 3, j0 = kg & 7;
        size_t off = ((((size_t)(s_ * 8 + ns) * 128 + kc) * 64 + q * 16 + ln)) * 8 + j0;
        *(ushort4*)&Wfh[off] = ohi;        // 8B-aligned
        *(ushort4*)&Wfl[off] = olo;
    }
}

// ---------------------------------------------------------------------------
// Prologue 2: x0 = (1/beta)*log(g/(1-g)) (plain layout); g -> A-frag (hi,lo)
// ---------------------------------------------------------------------------
__global__ __launch_bounds__(256) void init_kernel(const float* __restrict__ g_in,
                                                   const float* __restrict__ beta,
                                                   float* __restrict__ x,
                                                   unsigned short* __restrict__ gfh,
                                                   unsigned short* __restrict__ gfl) {
    int idx = blockIdx.x * 256 + threadIdx.x;
    int r = idx >> 12, c = idx & (NN - 1);
    float g = g_in[idx];
    x[idx] = logf(g / (1.0f - g)) / beta[c];
    unsigned short hi = f2bf(g);
    unsigned short lo = f2bf(g - bf2f(hi));
    size_t off = (((size_t)(c >> 5) * 4 + (r >> 4)) * 64 + ((c & 31) >> 3) * 16 + (r & 15)) * 8 + (c & 7);
    gfh[off] = hi;
    gfl[off] = lo;
}

// ---------------------------------------------------------------------------
// Prologue 3: max_x = 50 / max(beta); Prologue 4: zero the split-K counters.
// ---------------------------------------------------------------------------
__global__ __launch_bounds__(256) void maxx_kernel(const float* __restrict__ beta,
                                                   float* __restrict__ out) {
    __shared__ float red[256];
    float m = -1e30f;
    for (int i = threadIdx.x; i < NN; i += 256) m = fmaxf(m, beta[i]);
    red[threadIdx.x] = m;
    __syncthreads();
    for (int s = 128; s > 0; s >>= 1) {
        if (threadIdx.x < s) red[threadIdx.x] = fmaxf(red[threadIdx.x], red[threadIdx.x + s]);
        __syncthreads();
    }
    if (threadIdx.x == 0) out[0] = 50.0f / red[0];
}

__global__ __launch_bounds__(256) void zero_kernel(int* __restrict__ cnt, int n) {
    int i = blockIdx.x * 256 + threadIdx.x;
    if (i < n) cnt[i] = 0;
}

// ---------------------------------------------------------------------------
// One step, ONE dispatch. Grid 256 x 512. Block: k = bx>>5, s = bx&31
// (the 8 k-blocks of strip s share bx%8 -> same XCD under round-robin).
// Phase A: wave w (mh=w&1, nh=(w>>1)&1, kh=w>>2): 32x64 corner over its
//   256-wide K half; kh=1 dumps acc to LDS; kh=0 adds + writes P[k][s].
// Tail: __threadfence + atomicAdd(cnt[s]); last block (old==7) reduces the
//   8 P slices and runs the fused epilogue for strip s (split-K fixup).
// ---------------------------------------------------------------------------
__global__ __launch_bounds__(512, 2) void step_kernel(
    const unsigned short* __restrict__ gih, const unsigned short* __restrict__ gil,
    unsigned short* __restrict__ goh, unsigned short* __restrict__ gol,
    float* __restrict__ x,
    const unsigned short* __restrict__ Wfh,
    const unsigned short* __restrict__ Wfl,
    const float* __restrict__ bvec,
    const float* __restrict__ beta,
    const float* __restrict__ tau,
    const float* __restrict__ dt_ptr,
    const float* __restrict__ maxx_ptr,
    float* __restrict__ P,
    int* __restrict__ cnt,                    // this step's 32 counters
    float* __restrict__ gout_f32)             // non-null on last step only
{
    __shared__ float sacc[4][32][64];         // 32 KB: kh=1 wave acc dump
    __shared__ int last_flag;

    const int tid  = threadIdx.x;
    const int w    = tid >> 6;
    const int lane = tid & 63;
    const int q    = lane >> 4;
    const int l16  = lane & 15;

    const int bx = blockIdx.x;
    const int k  = bx >> 5;        // K-slice 0..7
    const int s  = bx & 31;        // strip 0..31

    const int mh = w & 1;
    const int nh = (w >> 1) & 1;
    const int kh = w >> 2;

    // ---------------- Phase A: GEMM partials ----------------
    f32x4 acc[2][4] = {};
#pragma unroll
    for (int it = 0; it < 8; ++it) {
        const int kc = k * 16 + kh * 8 + it;
        const size_t aBase = ((size_t)kc * 4) * 512 + lane * 8;
        const size_t bBase = (((size_t)(s * 8) * 128 + kc) * 64 + lane) * 8;
        bf16x8 ah[2], al[2], bh[4], bl[4];
#pragma unroll
        for (int mi = 0; mi < 2; ++mi) {
            const size_t a = aBase + (size_t)(mh * 2 + mi) * 512;
            ah[mi] = *(const bf16x8*)&gih[a];
            al[mi] = *(const bf16x8*)&gil[a];
        }
#pragma unroll
        for (int ni = 0; ni < 4; ++ni) {
            const size_t b = bBase + (size_t)(nh * 4 + ni) * 128 * 512;
            bh[ni] = *(const bf16x8*)&Wfh[b];
            bl[ni] = *(const bf16x8*)&Wfl[b];
        }
#pragma unroll
        for (int mi = 0; mi < 2; ++mi)
#pragma unroll
            for (int ni = 0; ni < 4; ++ni) {
                acc[mi][ni] = __builtin_amdgcn_mfma_f32_16x16x32_bf16(ah[mi], bh[ni], acc[mi][ni], 0, 0, 0);
                acc[mi][ni] = __builtin_amdgcn_mfma_f32_16x16x32_bf16(al[mi], bh[ni], acc[mi][ni], 0, 0, 0);
                acc[mi][ni] = __builtin_amdgcn_mfma_f32_16x16x32_bf16(ah[mi], bl[ni], acc[mi][ni], 0, 0, 0);
            }
    }

    if (kh == 1) {
#pragma unroll
        for (int mi = 0; mi < 2; ++mi)
#pragma unroll
            for (int ni = 0; ni < 4; ++ni)
#pragma unroll
                for (int rg = 0; rg < 4; ++rg)
                    sacc[w - 4][(mi * 4 + ni) * 4 + rg][lane] = acc[mi][ni][rg];
    }
    __syncthreads();
    if (kh == 0) {
        float* Pb = &P[((size_t)(k * NSTRIP + s) * 64) * 128];
#pragma unroll
        for (int mi = 0; mi < 2; ++mi)
#pragma unroll
            for (int ni = 0; ni < 4; ++ni)
#pragma unroll
                for (int rg = 0; rg < 4; ++rg) {
                    const int row = mh * 32 + mi * 16 + q * 4 + rg;
                    const int col = nh * 64 + ni * 16 + l16;
                    Pb[(size_t)row * 128 + col] = acc[mi][ni][rg] + sacc[w][(mi * 4 + ni) * 4 + rg][lane];
                }
    }

    // ---------------- split-K rendezvous ----------------
    __threadfence();                 // release P writes (device scope)
    __syncthreads();
    if (tid == 0) {
        int old = atomicAdd(&cnt[s], 1);
        last_flag = (old == NSLICE - 1);
    }
    __syncthreads();
    if (!last_flag) return;
    __threadfence();                 // acquire: P slices of all 8 blocks

    // ---------------- tail epilogue for strip s (1 block) ----------------
    // thread -> row m = tid>>3, 16 cols at c16 = (tid&7)*16
    const int m   = tid >> 3;
    const int c16 = (tid & 7) * 16;
    const int col0 = s * 128 + c16;

    float sum[16] = {};
#pragma unroll
    for (int kp = 0; kp < NPART; ++kp) {
        const float* p = &P[((size_t)(kp * NSTRIP + s) * 64 + m) * 128 + c16];
#pragma unroll
        for (int v = 0; v < 4; ++v) {
            float4 pv = *(const float4*)&p[v * 4];
            sum[v * 4 + 0] += pv.x; sum[v * 4 + 1] += pv.y;
            sum[v * 4 + 2] += pv.z; sum[v * 4 + 3] += pv.w;
        }
    }

    const float dt = *dt_ptr;
    const float mx = *maxx_ptr;
    float bb[16], be[16], tv[16], xo[16];
#pragma unroll
    for (int v = 0; v < 4; ++v) {
        float4 b4 = *(const float4*)&bvec[col0 + v * 4];
        float4 e4 = *(const float4*)&beta[col0 + v * 4];
        float4 t4 = *(const float4*)&tau[col0 + v * 4];
        bb[v*4+0]=b4.x; bb[v*4+1]=b4.y; bb[v*4+2]=b4.z; bb[v*4+3]=b4.w;
        be[v*4+0]=e4.x; be[v*4+1]=e4.y; be[v*4+2]=e4.z; be[v*4+3]=e4.w;
        tv[v*4+0]=t4.x; tv[v*4+1]=t4.y; tv[v*4+2]=t4.z; tv[v*4+3]=t4.w;
    }
    float* xp = &x[(size_t)m * NN + col0];
#pragma unroll
    for (int v = 0; v < 4; ++v) {
        float4 x4 = *(const float4*)&xp[v * 4];
        xo[v*4+0]=x4.x; xo[v*4+1]=x4.y; xo[v*4+2]=x4.z; xo[v*4+3]=x4.w;
    }

    float gg[16];
    unsigned short vh[16], vl[16];
#pragma unroll
    for (int j = 0; j < 16; ++j) {
        const float al = dt / tv[j];
        float xn = al * (sum[j] + bb[j]) + (1.0f - al) * xo[j];
        xn = fminf(fmaxf(xn, -mx), mx);
        float g = 1.0f / (1.0f + __expf(-be[j] * xn));
        xo[j] = xn;
        gg[j] = g;
        unsigned short hi = f2bf(g);
        vh[j] = hi;
        vl[j] = f2bf(g - bf2f(hi));
    }
#pragma unroll
    for (int v = 0; v < 4; ++v)
        *(float4*)&xp[v * 4] = {xo[v*4+0], xo[v*4+1], xo[v*4+2], xo[v*4+3]};

    // g A-frags: two 8-col groups (kg = col0, col0+8)
#pragma unroll
    for (int h = 0; h < 2; ++h) {
        const int kg = col0 + h * 8;
        size_t off = (((size_t)(kg >> 5) * 4 + (m >> 4)) * 64 + ((kg & 31) >> 3) * 16 + (m & 15)) * 8;
        *(ushort4*)&goh[off]     = {vh[h*8+0], vh[h*8+1], vh[h*8+2], vh[h*8+3]};
        *(ushort4*)&goh[off + 4] = {vh[h*8+4], vh[h*8+5], vh[h*8+6], vh[h*8+7]};
        *(ushort4*)&gol[off]     = {vl[h*8+0], vl[h*8+1], vl[h*8+2], vl[h*8+3]};
        *(ushort4*)&gol[off + 4] = {vl[h*8+4], vl[h*8+5], vl[h*8+6], vl[h*8+7]};
    }

    if (gout_f32) {
#pragma unroll
        for (int v = 0; v < 4; ++v)
            *(float4*)&gout_f32[(size_t)m * NN + col0 + v * 4] =
                {gg[v*4+0], gg[v*4+1], gg[v*4+2], gg[v*4+3]};
    }
}

// ---------------------------------------------------------------------------
extern "C" void kernel_launch(void* const* d_in, const int* in_sizes, int n_in,
                              void* d_out, int out_size, void* d_ws, size_t ws_size,
                              hipStream_t stream) {
    const float* state_g = (const float*)d_in[0];
    const float* W       = (const float*)d_in[1];
    const float* b       = (const float*)d_in[2];
    const float* beta    = (const float*)d_in[3];
    const float* tau     = (const float*)d_in[4];
    const float* dt      = (const float*)d_in[5];
    float* out = (float*)d_out;

    char* ws = (char*)d_ws;
    const size_t WH = (size_t)KK * NN * 2;    // 32 MB per W-frag array
    const size_t XB = (size_t)MM * NN * 4;    // 1 MB
    const size_t GB = (size_t)MM * NN * 2;    // 512 KB per g-frag array
    const size_t PB = (size_t)NPART * NSTRIP * 64 * 128 * 4;   // 8 MB
    unsigned short* Wfh = (unsigned short*)ws;
    unsigned short* Wfl = (unsigned short*)(ws + WH);
    float*          x   = (float*)(ws + 2 * WH);
    unsigned short* g0h = (unsigned short*)(ws + 2 * WH + XB);
    unsigned short* g0l = (unsigned short*)(ws + 2 * WH + XB + GB);
    unsigned short* g1h = (unsigned short*)(ws + 2 * WH + XB + 2 * GB);
    unsigned short* g1l = (unsigned short*)(ws + 2 * WH + XB + 3 * GB);
    float*          P   = (float*)(ws + 2 * WH + XB + 4 * GB);
    float*          mxp = (float*)(ws + 2 * WH + XB + 4 * GB + PB);
    int*            cnt = (int*)(ws + 2 * WH + XB + 4 * GB + PB + 256);
    const int nCnt = NSTEP * NSTRIP;          // 6400 ints

    symm_kernel<<<dim3(64, 64), 256, 0, stream>>>(W, Wfh, Wfl);
    init_kernel<<<(MM * NN) / 256, 256, 0, stream>>>(state_g, beta, x, g0h, g0l);
    maxx_kernel<<<1, 256, 0, stream>>>(beta, mxp);
    zero_kernel<<<(nCnt + 255) / 256, 256, 0, stream>>>(cnt, nCnt);

    unsigned short *gih = g0h, *gil = g0l, *goh = g1h, *gol = g1l;
    for (int st = 0; st < NSTEP; ++st) {
        float* of = (st == NSTEP - 1) ? out : nullptr;
        step_kernel<<<NSTRIP * NSLICE, 512, 0, stream>>>(
            gih, gil, goh, gol, x, Wfh, Wfl, b, beta, tau, dt, mxp,
            P, cnt + st * NSTRIP, of);
        unsigned short* tp;
        tp = gih; gih = goh; goh = tp;
        tp = gil; gil = gol; gol = tp;
    }
}

// Round 8
// 3831.376 us; speedup vs baseline: 4.6320x; 4.2722x over previous
//
#include <hip/hip_runtime.h>
#include <hip/hip_bf16.h>

// Problem constants (fixed shapes per reference setup_inputs; n_step = 200).
#define MM 64
#define NN 4096
#define KK 4096
#define NSTEP 200
#define NSLICE 8     // K-slice blocks per strip (block k = bx&7; same-XCD per k)
#define NSTRIP 32    // 128-column strips (block s = bx>>3)
#define NPART 8      // P slices (after intra-block kh 4-way LDS reduction)

typedef __bf16 bf16x8 __attribute__((ext_vector_type(8)));
typedef float  f32x4  __attribute__((ext_vector_type(4)));

static __device__ __forceinline__ unsigned short f2bf(float f) {
    __hip_bfloat16 h = __float2bfloat16(f);
    return __builtin_bit_cast(unsigned short, h);
}
static __device__ __forceinline__ float bf2f(unsigned short u) {
    __hip_bfloat16 h = __builtin_bit_cast(__hip_bfloat16, u);
    return __bfloat162float(h);
}

// Fragment layouts (mfma_f32_16x16x32_bf16, m89 mapping:
//   frag[lane=q*16+l16][j] = Mat[row16=l16][k=q*8+j]):
// A (g):  addr(m,kg) = ((kc*4 + (m>>4))*64 + q*16 + (m&15))*8 + j
// B (W):  addr(n,kg) = (((s*8 + ns)*128 + kc)*64 + q*16 + (n&15))*8 + j
// Partials P[part 8][s 32][row 64][col 128] fp32 (8 MB); part = k.

// ---------------------------------------------------------------------------
// Prologue 1: s = 0.5*(W[n][k]+W[k][n]), diag zero; (hi,lo) bf16 split,
// scattered into B-fragment order. 64x64 tiles, LDS transpose.
// ---------------------------------------------------------------------------
__global__ __launch_bounds__(256) void symm_kernel(const float* __restrict__ W,
                                                   unsigned short* __restrict__ Wfh,
                                                   unsigned short* __restrict__ Wfl) {
    __shared__ float T[64][65];
    const int tid = threadIdx.x;
    const int r0 = blockIdx.y * 64, c0 = blockIdx.x * 64;
#pragma unroll
    for (int i = 0; i < 4; ++i) {
        int lin = tid + i * 256;
        int cc  = lin >> 4;
        int r4  = (lin & 15) * 4;
        float4 v = *(const float4*)&W[(size_t)(c0 + cc) * NN + r0 + r4];
        T[cc][r4 + 0] = v.x; T[cc][r4 + 1] = v.y;
        T[cc][r4 + 2] = v.z; T[cc][r4 + 3] = v.w;
    }
    __syncthreads();
#pragma unroll
    for (int i = 0; i < 4; ++i) {
        int lin = tid + i * 256;
        int rr  = lin >> 4;
        int c4  = (lin & 15) * 4;
        float4 v = *(const float4*)&W[(size_t)(r0 + rr) * NN + c0 + c4];
        float d[4] = {v.x, v.y, v.z, v.w};
        ushort4 ohi, olo;
        unsigned short* ph = (unsigned short*)&ohi;
        unsigned short* pl = (unsigned short*)&olo;
#pragma unroll
        for (int j = 0; j < 4; ++j) {
            float sv = 0.5f * (d[j] + T[c4 + j][rr]);
            if (r0 + rr == c0 + c4 + j) sv = 0.0f;
            unsigned short hi = f2bf(sv);
            ph[j] = hi;
            pl[j] = f2bf(sv - bf2f(hi));
        }
        const int n  = r0 + rr;            // W row == output column
        const int kg = c0 + c4;            // 4-aligned
        const int s_ = n >> 7, ns = (n >> 4) & 7, ln = n & 15;
        const int kc = kg >> 5, q = (kg & 31) >> 3, j0 = kg & 7;
        size_t off = ((((size_t)(s_ * 8 + ns) * 128 + kc) * 64 + q * 16 + ln)) * 8 + j0;
        *(ushort4*)&Wfh[off] = ohi;        // 8B-aligned
        *(ushort4*)&Wfl[off] = olo;
    }
}

// ---------------------------------------------------------------------------
// Prologue 2: x0 = (1/beta)*log(g/(1-g)) (plain layout); g -> A-frag (hi,lo)
// ---------------------------------------------------------------------------
__global__ __launch_bounds__(256) void init_kernel(const float* __restrict__ g_in,
                                                   const float* __restrict__ beta,
                                                   float* __restrict__ x,
                                                   unsigned short* __restrict__ gfh,
                                                   unsigned short* __restrict__ gfl) {
    int idx = blockIdx.x * 256 + threadIdx.x;
    int r = idx >> 12, c = idx & (NN - 1);
    float g = g_in[idx];
    x[idx] = logf(g / (1.0f - g)) / beta[c];
    unsigned short hi = f2bf(g);
    unsigned short lo = f2bf(g - bf2f(hi));
    size_t off = (((size_t)(c >> 5) * 4 + (r >> 4)) * 64 + ((c & 31) >> 3) * 16 + (r & 15)) * 8 + (c & 7);
    gfh[off] = hi;
    gfl[off] = lo;
}

// ---------------------------------------------------------------------------
// Prologue 3: max_x = 50 / max(beta)
// ---------------------------------------------------------------------------
__global__ __launch_bounds__(256) void maxx_kernel(const float* __restrict__ beta,
                                                   float* __restrict__ out) {
    __shared__ float red[256];
    float m = -1e30f;
    for (int i = threadIdx.x; i < NN; i += 256) m = fmaxf(m, beta[i]);
    red[threadIdx.x] = m;
    __syncthreads();
    for (int s = 128; s > 0; s >>= 1) {
        if (threadIdx.x < s) red[threadIdx.x] = fmaxf(red[threadIdx.x], red[threadIdx.x + s]);
        __syncthreads();
    }
    if (threadIdx.x == 0) out[0] = 50.0f / red[0];
}

// ---------------------------------------------------------------------------
// GEMM partials: grid 256 = (strip s = bx>>3) x (kslice k = bx&7), 1024 thr
// (16 waves = 4 waves/SIMD for latency hiding; was 512/2-per-SIMD in r5).
// Wave w: mh=w&1, nh=(w>>1)&1, kh=w>>2 (4-way, 128-wide K quarter).
// kh>0 waves dump acc to LDS; kh==0 waves add the 3 partners and write
// P[k][s] (64x128 fp32) -> NPART=8. No fences, no atomics (kernel boundary
// is the global barrier -- rounds 6/7 showed in-kernel device-scope sync
// costs 40-70 us/step on this 8-XCD part).
// ---------------------------------------------------------------------------
__global__ __launch_bounds__(1024, 1) void gemm_kernel(
    const unsigned short* __restrict__ gfh,
    const unsigned short* __restrict__ gfl,
    const unsigned short* __restrict__ Wfh,
    const unsigned short* __restrict__ Wfl,
    float* __restrict__ P)
{
    __shared__ float sacc[12][32][64];   // 96 KB: kh=1..3 wave acc dump

    const int tid  = threadIdx.x;
    const int w    = tid >> 6;
    const int lane = tid & 63;
    const int q    = lane >> 4;
    const int l16  = lane & 15;

    const int s = blockIdx.x >> 3;
    const int k = blockIdx.x & 7;        // bx%8==k -> same-k blocks share an XCD (g L2 reuse)

    const int mh = w & 1;
    const int nh = (w >> 1) & 1;
    const int kh = w >> 2;               // 0..3

    f32x4 acc[2][4] = {};

#pragma unroll
    for (int it = 0; it < 4; ++it) {
        const int kc = k * 16 + kh * 4 + it;
        const size_t aBase = ((size_t)kc * 4) * 512 + lane * 8;          // + msub*512
        const size_t bBase = (((size_t)(s * 8) * 128 + kc) * 64 + lane) * 8;  // + nsub*65536
        bf16x8 ah[2], al[2], bh[4], bl[4];
#pragma unroll
        for (int mi = 0; mi < 2; ++mi) {
            const size_t a = aBase + (size_t)(mh * 2 + mi) * 512;
            ah[mi] = *(const bf16x8*)&gfh[a];
            al[mi] = *(const bf16x8*)&gfl[a];
        }
#pragma unroll
        for (int ni = 0; ni < 4; ++ni) {
            const size_t b = bBase + (size_t)(nh * 4 + ni) * 128 * 512;
            bh[ni] = *(const bf16x8*)&Wfh[b];
            bl[ni] = *(const bf16x8*)&Wfl[b];
        }
#pragma unroll
        for (int mi = 0; mi < 2; ++mi)
#pragma unroll
            for (int ni = 0; ni < 4; ++ni) {
                acc[mi][ni] = __builtin_amdgcn_mfma_f32_16x16x32_bf16(ah[mi], bh[ni], acc[mi][ni], 0, 0, 0);
                acc[mi][ni] = __builtin_amdgcn_mfma_f32_16x16x32_bf16(al[mi], bh[ni], acc[mi][ni], 0, 0, 0);
                acc[mi][ni] = __builtin_amdgcn_mfma_f32_16x16x32_bf16(ah[mi], bl[ni], acc[mi][ni], 0, 0, 0);
            }
    }

    if (kh > 0) {
#pragma unroll
        for (int mi = 0; mi < 2; ++mi)
#pragma unroll
            for (int ni = 0; ni < 4; ++ni)
#pragma unroll
                for (int rg = 0; rg < 4; ++rg)
                    sacc[w - 4][(mi * 4 + ni) * 4 + rg][lane] = acc[mi][ni][rg];
    }
    __syncthreads();
    if (kh == 0) {
        float* Pb = &P[((size_t)(k * NSTRIP + s) * 64) * 128];
#pragma unroll
        for (int mi = 0; mi < 2; ++mi)
#pragma unroll
            for (int ni = 0; ni < 4; ++ni)
#pragma unroll
                for (int rg = 0; rg < 4; ++rg) {
                    const int idx = (mi * 4 + ni) * 4 + rg;
                    const int row = mh * 32 + mi * 16 + q * 4 + rg;
                    const int col = nh * 64 + ni * 16 + l16;
                    float v = acc[mi][ni][rg]
                            + sacc[w][idx][lane]       // partner kh=1 (wave w+4)
                            + sacc[w + 4][idx][lane]   // partner kh=2 (wave w+8)
                            + sacc[w + 8][idx][lane];  // partner kh=3 (wave w+12)
                    Pb[(size_t)row * 128 + col] = v;
                }
    }
}

// ---------------------------------------------------------------------------
// Epilogue: 128 blocks x 256 thr; thread t -> (m = t>>9, n0 = (t&511)*8).
// Sums 8 partials, applies b/alpha/clip/sigmoid, updates x (plain), writes
// g hi/lo A-fragments for the next step; plain fp32 g on the last step.
// ---------------------------------------------------------------------------
__global__ __launch_bounds__(256) void epi_kernel(
    const float* __restrict__ P,
    float* __restrict__ x,
    unsigned short* __restrict__ gfh_out,
    unsigned short* __restrict__ gfl_out,
    const float* __restrict__ bvec,
    const float* __restrict__ beta,
    const float* __restrict__ tau,
    const float* __restrict__ dt_ptr,
    const float* __restrict__ maxx_ptr,
    float* __restrict__ gout_f32)             // non-null on last step only
{
    const int t  = blockIdx.x * 256 + threadIdx.x;   // 0..32767
    const int m  = t >> 9;
    const int n0 = (t & 511) * 8;
    const int s  = n0 >> 7;

    float sum[8] = {};
#pragma unroll
    for (int k = 0; k < NPART; ++k) {
        const float* p = &P[((size_t)(k * NSTRIP + s) * 64 + m) * 128 + (n0 & 127)];
        float4 p0 = *(const float4*)&p[0];
        float4 p1 = *(const float4*)&p[4];
        sum[0] += p0.x; sum[1] += p0.y; sum[2] += p0.z; sum[3] += p0.w;
        sum[4] += p1.x; sum[5] += p1.y; sum[6] += p1.z; sum[7] += p1.w;
    }

    const float dt = *dt_ptr;
    const float mx = *maxx_ptr;
    float4 b0 = *(const float4*)&bvec[n0], b1 = *(const float4*)&bvec[n0 + 4];
    float4 e0 = *(const float4*)&beta[n0], e1 = *(const float4*)&beta[n0 + 4];
    float4 t0 = *(const float4*)&tau[n0],  t1 = *(const float4*)&tau[n0 + 4];
    float bb[8] = {b0.x, b0.y, b0.z, b0.w, b1.x, b1.y, b1.z, b1.w};
    float be[8] = {e0.x, e0.y, e0.z, e0.w, e1.x, e1.y, e1.z, e1.w};
    float tv[8] = {t0.x, t0.y, t0.z, t0.w, t1.x, t1.y, t1.z, t1.w};

    float* xp = &x[(size_t)m * NN + n0];
    float4 x0 = *(const float4*)&xp[0], x1 = *(const float4*)&xp[4];
    float xo[8] = {x0.x, x0.y, x0.z, x0.w, x1.x, x1.y, x1.z, x1.w};

    float gg[8];
    unsigned short vh[8], vl[8];
#pragma unroll
    for (int j = 0; j < 8; ++j) {
        const float al = dt / tv[j];
        float xn = al * (sum[j] + bb[j]) + (1.0f - al) * xo[j];
        xn = fminf(fmaxf(xn, -mx), mx);
        float g = 1.0f / (1.0f + __expf(-be[j] * xn));
        xo[j] = xn;
        gg[j] = g;
        unsigned short hi = f2bf(g);
        vh[j] = hi;
        vl[j] = f2bf(g - bf2f(hi));
    }
    *(float4*)&xp[0] = {xo[0], xo[1], xo[2], xo[3]};
    *(float4*)&xp[4] = {xo[4], xo[5], xo[6], xo[7]};

    // A-fragment address for (m, kg = n0..n0+7): j spans 0..7 contiguously
    size_t off = (((size_t)(n0 >> 5) * 4 + (m >> 4)) * 64 + ((n0 & 31) >> 3) * 16 + (m & 15)) * 8;
    *(ushort4*)&gfh_out[off]     = {vh[0], vh[1], vh[2], vh[3]};
    *(ushort4*)&gfh_out[off + 4] = {vh[4], vh[5], vh[6], vh[7]};
    *(ushort4*)&gfl_out[off]     = {vl[0], vl[1], vl[2], vl[3]};
    *(ushort4*)&gfl_out[off + 4] = {vl[4], vl[5], vl[6], vl[7]};

    if (gout_f32) {
        *(float4*)&gout_f32[(size_t)m * NN + n0]     = {gg[0], gg[1], gg[2], gg[3]};
        *(float4*)&gout_f32[(size_t)m * NN + n0 + 4] = {gg[4], gg[5], gg[6], gg[7]};
    }
}

// ---------------------------------------------------------------------------
extern "C" void kernel_launch(void* const* d_in, const int* in_sizes, int n_in,
                              void* d_out, int out_size, void* d_ws, size_t ws_size,
                              hipStream_t stream) {
    const float* state_g = (const float*)d_in[0];
    const float* W       = (const float*)d_in[1];
    const float* b       = (const float*)d_in[2];
    const float* beta    = (const float*)d_in[3];
    const float* tau     = (const float*)d_in[4];
    const float* dt      = (const float*)d_in[5];
    float* out = (float*)d_out;

    char* ws = (char*)d_ws;
    const size_t WH = (size_t)KK * NN * 2;    // 32 MB per W-frag array
    const size_t XB = (size_t)MM * NN * 4;    // 1 MB
    const size_t GB = (size_t)MM * NN * 2;    // 512 KB per g-frag array
    const size_t PB = (size_t)NPART * NSTRIP * 64 * 128 * 4;   // 8 MB
    unsigned short* Wfh = (unsigned short*)ws;
    unsigned short* Wfl = (unsigned short*)(ws + WH);
    float*          x   = (float*)(ws + 2 * WH);
    unsigned short* g0h = (unsigned short*)(ws + 2 * WH + XB);
    unsigned short* g0l = (unsigned short*)(ws + 2 * WH + XB + GB);
    unsigned short* g1h = (unsigned short*)(ws + 2 * WH + XB + 2 * GB);
    unsigned short* g1l = (unsigned short*)(ws + 2 * WH + XB + 3 * GB);
    float*          P   = (float*)(ws + 2 * WH + XB + 4 * GB);
    float*          mxp = (float*)(ws + 2 * WH + XB + 4 * GB + PB);

    symm_kernel<<<dim3(64, 64), 256, 0, stream>>>(W, Wfh, Wfl);
    init_kernel<<<(MM * NN) / 256, 256, 0, stream>>>(state_g, beta, x, g0h, g0l);
    maxx_kernel<<<1, 256, 0, stream>>>(beta, mxp);

    unsigned short *gih = g0h, *gil = g0l, *goh = g1h, *gol = g1l;
    for (int st = 0; st < NSTEP; ++st) {
        float* of = (st == NSTEP - 1) ? out : nullptr;
        gemm_kernel<<<NSTRIP * NSLICE, 1024, 0, stream>>>(gih, gil, Wfh, Wfl, P);
        epi_kernel<<<128, 256, 0, stream>>>(P, x, goh, gol, b, beta, tau, dt, mxp, of);
        unsigned short* tp;
        tp = gih; gih = goh; goh = tp;
        tp = gil; gil = gol; gol = tp;
    }
}